// Round 13
// baseline (991.780 us; speedup 1.0000x reference)
//
#include <hip/hip_runtime.h>

#define H_ 384
#define W_ 512
#define N_ (H_*W_)        // 196608
#define B_ 2
#define T_ 1048576
#define TMASK_ 0xFFFFFu
#define G2N_ ((2*N_)/256) // 1536
#define G2T_ ((2*T_)/256) // 8192
#define CHS_ 64           // doubles per channel accumulator block (8 subs x 8-double spacing)
// scalD layout (doubles), all accumulators 8-way sub-slot spread (64B apart):
//   [0..191]   zeroD (stays 0; beta num/den at it==0)
//   rz  [b][it] at 192   + b*2688 + it*192   (it=0..13)
//   pAp [b][it] at 5568  + b*2496 + it*192   (it=0..12)
//   GN acc      at 10560 + L*512 + bg*128 (+j*8 sum, +64+j*8 sumsq)
#define RZ0_ 192
#define RZB_ 2688
#define PAP0_ 5568
#define PAPB_ 2496
#define GN0_ 10560

__device__ __forceinline__ int prime(int d){
  switch(d){
    case 0: return 73856093;
    case 1: return 19349663;
    case 2: return 83492791;
    case 3: return 49979687;
    default: return 24036583;
  }
}

__device__ __forceinline__ float clampScale(float s){ return fminf(fmaxf(s,1e-5f),1.0f); }

__device__ __forceinline__ double blockReduceD(double v){
  __shared__ double sh[4];
  for(int s=32;s>0;s>>=1) v += __shfl_down(v,s,64);
  int lane=threadIdx.x&63, w=threadIdx.x>>6;
  if(lane==0) sh[w]=v;
  __syncthreads();
  double r = sh[0]+sh[1]+sh[2]+sh[3];
  __syncthreads();
  return r;
}
__device__ __forceinline__ double waveReduceD(double v){
  for(int s=32;s>0;s>>=1) v += __shfl_down(v,s,64);
  return v;   // valid in lane 0
}
__device__ __forceinline__ float blockReduceMaxF(float v){
  __shared__ float sh[4];
  for(int s=32;s>0;s>>=1) v = fmaxf(v,__shfl_down(v,s,64));
  int lane=threadIdx.x&63, w=threadIdx.x>>6;
  if(lane==0) sh[w]=v;
  __syncthreads();
  float r = fmaxf(fmaxf(sh[0],sh[1]),fmaxf(sh[2],sh[3]));
  __syncthreads();
  return r;
}

// spread atomic into 8 sub-slots (separate 64B lines); consumer sums 8
__device__ __forceinline__ void redAdd(double* base, int c, double v){
  atomicAdd(&base[c*CHS_ + ((blockIdx.x&7)<<3)], v);
}
__device__ __forceinline__ float redSum(const double* base, int c){
  double s=0.0;
  #pragma unroll
  for(int j=0;j<8;j++) s += base[c*CHS_ + j*8];
  return (float)s;
}

// ---------------- CNN kernels ----------------

__global__ __launch_bounds__(256) void k_maxes(const float4* img4, const float4* feat4, float* scal){
  const int PB = (3*N_)/4;
  for(int b=0;b<2;b++){
    float lm=0.f, lf=0.f;
    for(int idx = blockIdx.x*256+threadIdx.x; idx<PB; idx += gridDim.x*256){
      float4 a=img4[(size_t)b*PB+idx], c=feat4[(size_t)b*PB+idx];
      lm=fmaxf(lm, fmaxf(fmaxf(a.x,a.y),fmaxf(a.z,a.w)));
      lf=fmaxf(lf, fmaxf(fmaxf(c.x,c.y),fmaxf(c.z,c.w)));
    }
    lm=blockReduceMaxF(lm); lf=blockReduceMaxF(lf);
    if(threadIdx.x==0){
      atomicMax((int*)&scal[b],   __float_as_int(lm));
      atomicMax((int*)&scal[2+b], __float_as_int(lf));
    }
  }
}

// pre-transpose all conv weights into wtT[tap*16+oc] (one 50KB pass)
__global__ __launch_bounds__(256) void k_wt(const float* w1,const float* w2,const float* wd1,const float* wd2,
                                            float* t){
  int idx = blockIdx.x*256+threadIdx.x;   // grid 49 blocks, 12544 elems
  if(idx>=12544) return;
  if(idx<1536){ int oc=idx&15, tap=idx>>4; t[idx]=w1[oc*96+tap]; }
  else if(idx<5632){ int r=idx-1536; int oc=r&15, tap=r>>4; t[idx]=w2[oc*256+tap]; }
  else if(idx<7936){ int r=idx-5632; int oc=r&15, tap=r>>4; t[idx]=wd1[oc*144+tap]; }
  else { int r=idx-7936; int oc=r&15, tap=r>>4; t[idx]=wd2[oc*288+tap]; }
}

// accumulate NCH channels for TWO vertically-adjacent outputs (oy0, oy0+1):
// weight LDS reads shared between both outputs -> half the LDS issue per output.
template<bool SCALEA,bool GN,int NCH,int IC,int K,int S,bool EDGE,int IH,int IW>
__device__ __forceinline__ void conv_accum2(const float* __restrict__ plane0, int icBase, float sA,
                                            int oy0, int ox, const float* wlds,
                                            float acc0[16], float acc1[16],
                                            const float* gmf, const float* grs,
                                            const float* ggm, const float* gbt){
  for(int ic=0; ic<NCH; ic++){
    const float* plane = plane0 + (size_t)ic*IH*IW;
    float mf=0.f, rs=0.f, gm=0.f, bt=0.f;
    if(GN){ mf=gmf[ic]; rs=grs[ic]; gm=ggm[ic]; bt=gbt[ic]; }
    #pragma unroll
    for(int ky=0;ky<K;ky++){
      int iy0 = oy0*S + ky - 1;
      int iy1 = iy0 + S;
      int cy0 = min(max(iy0,0),IH-1), cy1 = min(max(iy1,0),IH-1);
      bool yin0 = (iy0>=0)&&(iy0<IH), yin1 = (iy1>=0)&&(iy1<IH);
      const float* row0 = plane + cy0*IW;
      const float* row1 = plane + cy1*IW;
      #pragma unroll
      for(int kx=0;kx<K;kx++){
        int ix = ox*S + kx - 1;
        float v0, v1;
        if(EDGE){
          int cx = min(max(ix,0),IW-1);
          v0 = row0[cx]; v1 = row1[cx];
          if(SCALEA){ v0 = v0 / sA; v1 = v1 / sA; }
          if(GN){ v0 = fmaxf((v0-mf)*rs*gm+bt, 0.f); v1 = fmaxf((v1-mf)*rs*gm+bt, 0.f); }
        } else {
          bool xin = (ix>=0)&&(ix<IW);
          if(xin && yin0){
            v0 = row0[ix];
            if(SCALEA) v0 = v0 / sA;
            if(GN)     v0 = fmaxf((v0-mf)*rs*gm+bt, 0.f);
          } else v0 = 0.f;
          if(xin && yin1){
            v1 = row1[ix];
            if(SCALEA) v1 = v1 / sA;
            if(GN)     v1 = fmaxf((v1-mf)*rs*gm+bt, 0.f);
          } else v1 = 0.f;
        }
        const float4* wp = (const float4*)&wlds[(((icBase+ic)*K+ky)*K+kx)*16];
        #pragma unroll
        for(int q=0;q<4;q++){
          float4 w4 = wp[q];
          acc0[4*q+0] += v0*w4.x; acc1[4*q+0] += v1*w4.x;
          acc0[4*q+1] += v0*w4.y; acc1[4*q+1] += v1*w4.y;
          acc0[4*q+2] += v0*w4.z; acc1[4*q+2] += v1*w4.z;
          acc0[4*q+3] += v0*w4.w; acc1[4*q+3] += v1*w4.w;
        }
      }
    }
  }
}

// conv OC=16, BS=64 (1 wave), one thread = TWO y-adjacent pixels, all 16 oc;
// weights LDS-staged from pre-transposed wtT; fused GN partial sums of OUTPUT;
// optional inline /max of A; inline GN+relu of A/B.
template<bool SCALEA,bool GNA,bool GNB,int ICA,int ICB,int K,int S,bool EDGE,int IH,int IW,int OH,int OW>
__global__ __launch_bounds__(64) void k_convT(const float* __restrict__ inA, const float* __restrict__ inB,
                        const float* __restrict__ wtT, const float* __restrict__ bias,
                        float* __restrict__ out, double* gnaccOut, const float* scal,
                        const double* accA, const float* gA, const float* bA,
                        const double* accB, const float* gB, const float* bB){
  constexpr int IC = ICA+ICB;
  __shared__ float wlds[IC*K*K*16];
  __shared__ float blds[16];
  __shared__ float gnA_mf[16], gnA_rs[16], gnA_gm[16], gnA_bt[16];
  __shared__ float gnB_mf[16], gnB_rs[16], gnB_gm[16], gnB_bt[16];
  for(int i=threadIdx.x; i<IC*K*K*4; i+=64)
    ((float4*)wlds)[i] = ((const float4*)wtT)[i];
  int idx = blockIdx.x*64+threadIdx.x;   // grid exactly B*(OH/2)*OW/64 ((OH/2)*OW%64==0: block single-b)
  int ox = idx % OW; int t=idx/OW; int oyh=t%(OH/2); int b=t/(OH/2);
  int oy0 = oyh*2;
  if(threadIdx.x<16){
    int c = threadIdx.x;
    blds[c]=bias[c];
    double len = 8.0*(double)(IH*IW);
    if(GNA){
      const double* ba = accA + (b*2 + (c>>3))*128;
      double s=0.0,s2=0.0;
      #pragma unroll
      for(int j=0;j<8;j++){ s+=ba[j*8]; s2+=ba[64+j*8]; }
      double mean = s/len; double var = s2/len - mean*mean;
      gnA_rs[c] = (float)(1.0/sqrt(var + 1e-5));
      gnA_mf[c] = (float)mean;
      gnA_gm[c] = gA[c]; gnA_bt[c] = bA[c];
    }
    if(GNB){
      const double* bb = accB + (b*2 + (c>>3))*128;
      double s=0.0,s2=0.0;
      #pragma unroll
      for(int j=0;j<8;j++){ s+=bb[j*8]; s2+=bb[64+j*8]; }
      double mean = s/len; double var = s2/len - mean*mean;
      gnB_rs[c] = (float)(1.0/sqrt(var + 1e-5));
      gnB_mf[c] = (float)mean;
      gnB_gm[c] = gB[c]; gnB_bt[c] = bB[c];
    }
  }
  __syncthreads();
  float sA = SCALEA ? clampScale(scal[b]) : 1.0f;
  float acc0[16], acc1[16];
  #pragma unroll
  for(int oc=0;oc<16;oc++){ acc0[oc]=0.f; acc1[oc]=0.f; }
  conv_accum2<SCALEA,GNA,ICA,IC,K,S,EDGE,IH,IW>(inA + (size_t)b*ICA*IH*IW, 0, sA, oy0, ox, wlds,
                                                acc0, acc1, gnA_mf,gnA_rs,gnA_gm,gnA_bt);
  if(ICB>0)
    conv_accum2<false,GNB,(ICB>0?ICB:1),IC,K,S,EDGE,IH,IW>(inB + (size_t)b*ICB*IH*IW, ICA, 1.0f, oy0, ox, wlds,
                                                acc0, acc1, gnB_mf,gnB_rs,gnB_gm,gnB_bt);
  double sl=0.0,s2l=0.0,sh=0.0,s2h=0.0;
  #pragma unroll
  for(int oc=0;oc<16;oc++){
    float vv0 = acc0[oc] + blds[oc];
    float vv1 = acc1[oc] + blds[oc];
    out[(((size_t)b*16+oc)*OH+oy0)*OW+ox]   = vv0;
    out[(((size_t)b*16+oc)*OH+oy0+1)*OW+ox] = vv1;
    double d0=(double)vv0, d1=(double)vv1;
    if(oc<8){ sl += d0+d1; s2l += d0*d0+d1*d1; }
    else    { sh += d0+d1; s2h += d0*d0+d1*d1; }
  }
  sl=waveReduceD(sl); s2l=waveReduceD(s2l);
  sh=waveReduceD(sh); s2h=waveReduceD(s2h);
  if(threadIdx.x==0){
    int sub = (blockIdx.x&7)<<3;
    atomicAdd(&gnaccOut[(b*2+0)*128 + sub],      sl);
    atomicAdd(&gnaccOut[(b*2+0)*128 + 64 + sub], s2l);
    atomicAdd(&gnaccOut[(b*2+1)*128 + sub],      sh);
    atomicAdd(&gnaccOut[(b*2+1)*128 + 64 + sub], s2h);
  }
}

// fused GN(+relu) applied per tap, then half-pixel bilinear resize (edge clamp)
__global__ __launch_bounds__(256) void k_resizeGN(const float* in, float* out, const double* acc,
                                                  const float* gamma, const float* beta,
                                                  int IH, int IW, int OH, int OW){
  int idx = blockIdx.x*256 + threadIdx.x;
  int total = B_*16*OH*OW;
  if(idx>=total) return;
  int ox = idx%OW; int t=idx/OW; int oy=t%OH; t/=OH;   // t = b*16+c
  int c = t%16, b = t/16;
  const double* ba = acc + (b*2 + (c>>3))*128;
  double s=0.0,s2=0.0;
  #pragma unroll
  for(int j=0;j<8;j++){ s+=ba[j*8]; s2+=ba[64+j*8]; }
  double len = 8.0*(double)(IH*IW);
  double mean = s/len;
  double var = s2/len - mean*mean;
  float rstd = (float)(1.0/sqrt(var + 1e-5));
  float mf = (float)mean;
  float g = gamma[c], be = beta[c];
  const float* plane = in + (size_t)t*IH*IW;
  float sy = (float)IH/(float)OH, sx=(float)IW/(float)OW;
  float fy = (oy+0.5f)*sy-0.5f, fx=(ox+0.5f)*sx-0.5f;
  float fy0 = floorf(fy), fx0=floorf(fx);
  float ty = fy-fy0, tx = fx-fx0;
  int y0 = min(max((int)fy0,0),IH-1), y1 = min(max((int)fy0+1,0),IH-1);
  int x0 = min(max((int)fx0,0),IW-1), x1 = min(max((int)fx0+1,0),IW-1);
  float v00=fmaxf((plane[y0*IW+x0]-mf)*rstd*g+be,0.f);
  float v01=fmaxf((plane[y0*IW+x1]-mf)*rstd*g+be,0.f);
  float v10=fmaxf((plane[y1*IW+x0]-mf)*rstd*g+be,0.f);
  float v11=fmaxf((plane[y1*IW+x1]-mf)*rstd*g+be,0.f);
  out[idx] = (1.f-ty)*((1.f-tx)*v00+tx*v01) + ty*((1.f-tx)*v10+tx*v11);
}

// conf head: TWO y-adjacent pixels per thread (shares input rows)
__global__ __launch_bounds__(256) void k_conv5(const float* in, const float* wf, const float* bf,
                                               float* confr, float* scal){
  int idx = blockIdx.x*256 + threadIdx.x;   // grid exactly B*(N/2)/256
  int ph = idx % (N_/2); int b = idx / (N_/2);
  int oyh = ph / W_, ox = ph % W_;
  int oy0 = oyh*2;
  float acc0 = bf[0], acc1 = bf[0];
  for(int ic=0; ic<16; ic++){
    const float* plane = in + ((size_t)b*16+ic)*N_;
    #pragma unroll
    for(int ky=0;ky<3;ky++){
      int iy0 = min(max(oy0+ky-1,0),H_-1);
      int iy1 = min(max(oy0+ky,0),H_-1);
      const float* row0 = plane + iy0*W_;
      const float* row1 = plane + iy1*W_;
      #pragma unroll
      for(int kx=0;kx<3;kx++){
        int ix = min(max(ox+kx-1,0),W_-1);
        float w = wf[(ic*3+ky)*3+kx];
        acc0 += row0[ix]*w;
        acc1 += row1[ix]*w;
      }
    }
  }
  float c0 = 0.5f*(tanhf(acc0)+1.0f);
  float c1 = 0.5f*(tanhf(acc1)+1.0f);
  confr[(size_t)b*N_ + oy0*W_ + ox]     = c0;
  confr[(size_t)b*N_ + (oy0+1)*W_ + ox] = c1;
  float mx = blockReduceMaxF(fmaxf(c0,c1));
  if(threadIdx.x==0) atomicMax((int*)&scal[4], __float_as_int(mx));
}

// ---------------- bilateral solver setup (both batches merged) ----------------

__global__ __launch_bounds__(256) void k_px1(const float* feat, const float* scal,
                                             int* hpix, int2* cpix2, int* winner){
  int idx = blockIdx.x*256 + threadIdx.x;   // grid exactly 2N/256
  int b = idx / N_, pix = idx % N_;
  int y = pix / W_, x = pix % W_;
  float sF = clampScale(scal[2+b]);
  const float* fb = feat + (size_t)b*3*N_;
  // exact reference eval order, no FMA contraction (coords are integer-binned)
  float R  = __fmul_rn(__fdiv_rn(fb[pix],      sF), 255.0f);
  float G  = __fmul_rn(__fdiv_rn(fb[N_+pix],   sF), 255.0f);
  float Bl = __fmul_rn(__fdiv_rn(fb[2*N_+pix], sF), 255.0f);
  float Y = __fadd_rn(__fadd_rn(__fadd_rn(__fmul_rn(0.299f,R),     __fmul_rn(0.587f,G)),  __fmul_rn(0.114f,Bl)), 0.0f);
  float U = __fadd_rn(__fadd_rn(__fadd_rn(__fmul_rn(-0.168736f,R), __fmul_rn(-0.331264f,G)), __fmul_rn(0.5f,Bl)), 128.0f);
  float V = __fadd_rn(__fadd_rn(__fadd_rn(__fmul_rn(0.5f,R),       __fmul_rn(-0.418688f,G)), __fmul_rn(-0.081312f,Bl)), 128.0f);
  int c[5];
  c[0] = (int)floorf(__fdiv_rn((float)x, 7.0f));
  c[1] = (int)floorf(__fdiv_rn((float)y, 7.0f));
  c[2] = (int)floorf(__fdiv_rn(Y, 8.0f));
  c[3] = (int)floorf(__fdiv_rn(U, 2.0f));
  c[4] = (int)floorf(__fdiv_rn(V, 2.0f));
  unsigned hh = 0;
  #pragma unroll
  for(int d=0;d<5;d++) hh += (unsigned)c[d]*(unsigned)prime(d);
  hh &= TMASK_;
  hpix[idx]=(int)hh;
  cpix2[idx]=make_int2(c[0] | (c[1]<<10) | (c[2]<<20), c[3] | (c[4]<<10));
  atomicMax(&winner[(size_t)b*T_+(int)hh], pix);   // last-writer (max pix) wins = XLA scatter
}

// --- atomic-free 3-phase compaction ---

__global__ __launch_bounds__(256) void k_cnt(const int* winner, int* bcnt){
  int t = blockIdx.x*256 + threadIdx.x;   // grid exactly 2T/256
  bool occ = winner[t] >= 0;
  __shared__ int wc[4];
  unsigned long long mk = __ballot(occ);
  int lane = threadIdx.x & 63, w = threadIdx.x >> 6;
  if(lane==0) wc[w] = __popcll(mk);
  __syncthreads();
  if(threadIdx.x==0) bcnt[blockIdx.x] = wc[0]+wc[1]+wc[2]+wc[3];
}

__global__ __launch_bounds__(256) void k_scan(const int* bcnt, int* boff, int* count){
  __shared__ int sh[256];
  __shared__ int carry;
  if(threadIdx.x==0) carry=0;
  __syncthreads();
  for(int chunk=0; chunk<32; ++chunk){
    if(chunk==16){
      if(threadIdx.x==0){ count[0]=carry; carry=0; }
      __syncthreads();
    }
    int v = bcnt[chunk*256+threadIdx.x];
    sh[threadIdx.x]=v;
    __syncthreads();
    for(int s2=1;s2<256;s2<<=1){
      int add = (threadIdx.x>=s2)? sh[threadIdx.x-s2] : 0;
      __syncthreads();
      sh[threadIdx.x]+=add;
      __syncthreads();
    }
    int incl = sh[threadIdx.x];
    boff[chunk*256+threadIdx.x] = carry + incl - v;
    __syncthreads();
    if(threadIdx.x==255) carry += incl;
    __syncthreads();
  }
  if(threadIdx.x==0) count[1]=carry;
}

__global__ __launch_bounds__(256) void k_cmp(const int* winner, const int* boff,
                                             int2* cidx2, int* slot_of){
  int t = blockIdx.x*256 + threadIdx.x;   // grid exactly 2T/256
  int b = t / T_;
  int wn = winner[t];
  bool occ = wn >= 0;
  __shared__ int wc[4];
  unsigned long long mk = __ballot(occ);
  int lane = threadIdx.x & 63, w = threadIdx.x >> 6;
  if(lane==0) wc[w] = __popcll(mk);
  __syncthreads();
  int wpre = 0;
  for(int k2=0;k2<4;k2++) if(k2<w) wpre += wc[k2];
  if(occ){
    int li = boff[blockIdx.x] + wpre + __popcll(mk & ((1ull<<lane)-1ull));
    int gi = b*N_ + li;
    cidx2[t] = make_int2(gi, wn);
    slot_of[gi] = t - b*T_;    // local slot hh
  }
}

// conf normalize + splat: winner plain-stores; non-winners (~10%) atomicAdd into extras
__global__ __launch_bounds__(256) void k_px3(int* hpix_gpix, const int2* cidx2, const float* confr,
                                             const float* scal, float* confout, const float* pred,
                                             float* mcomp, float4* splat4, float* mcompE, float* splatE){
  int idx = blockIdx.x*256 + threadIdx.x;   // grid exactly 2N/256
  int b = idx / N_, pix = idx % N_;
  int2 cw = cidx2[(size_t)b*T_ + hpix_gpix[idx]];
  int gi = cw.x;
  hpix_gpix[idx] = gi;
  float w = confr[idx] / fmaxf(scal[4], 1e-5f);
  confout[idx] = w;
  const float* pb = pred + (size_t)b*3*N_;
  float v0 = __fmul_rn(w, pb[pix]);
  float v1 = __fmul_rn(w, pb[N_+pix]);
  float v2 = __fmul_rn(w, pb[2*N_+pix]);
  if(cw.y == pix){
    splat4[gi] = make_float4(v0,v1,v2,w);
    mcomp[gi] = 1.0f;
  } else {
    float* s = splatE + 4*(size_t)gi;
    atomicAdd(s+0, v0);
    atomicAdd(s+1, v1);
    atomicAdd(s+2, v2);
    atomicAdd(s+3, w);
    atomicAdd(&mcompE[gi], 1.0f);
  }
}

// fused: merge extras + neighbor-table build + first bisto iter (n0=1)
__global__ __launch_bounds__(256) void k_bisto0(const int* count, const int* slot_of,
                      const int2* cpix2, const int2* cidx2, int* nbr,
                      float* mcomp, const float* mcompE, float4* splat4, const float4* splatE4,
                      float* nd){
  int i = blockIdx.x*256 + threadIdx.x;     // grid exactly 2N/256
  int b = i / N_, li = i - b*N_;
  if(li >= count[b]) return;
  int hh = slot_of[i];
  const int2* c2b = cidx2 + (size_t)b*T_;
  int2 cself = c2b[hh];
  int2 cp = cpix2[(size_t)b*N_ + cself.y];
  float4 sp = splat4[i]; float4 se = splatE4[i];
  sp.x+=se.x; sp.y+=se.y; sp.z+=se.z; sp.w+=se.w;
  splat4[i]=sp;
  float mTot = mcomp[i] + mcompE[i];
  mcomp[i]=mTot;
  float bv = 10.f;                          // 10*n with n=1
  #pragma unroll
  for(int j=0;j<10;j++){
    int d=j>>1; int off=(j&1)?1:-1;
    unsigned nh = ((unsigned)hh + (unsigned)(off*prime(d))) & TMASK_;
    int nb = -1;
    int2 cn2 = c2b[nh];
    if(cn2.y>=0){
      int2 cn = cpix2[(size_t)b*N_ + cn2.y];
      int e0 = cp.x + (d==0?off: d==1?off*(1<<10) : d==2?off*(1<<20) : 0);
      int e1 = cp.y + (d==3?off: d==4?off*(1<<10) : 0);
      if(cn.x==e0 && cn.y==e1) nb = cn2.x;
    }
    nbr[(size_t)j*(2*N_)+i]=nb;
    if(nb>=0) bv += 1.0f;                   // neighbor n = 1
  }
  nd[i] = sqrtf(1.0f*mTot/(bv+1e-12f));
}

__global__ __launch_bounds__(256) void k_bisto(const int* count, const int* nbr,
                                               const float* ns, float* nd, const float* mc){
  int i = blockIdx.x*256 + threadIdx.x;
  int b = i / N_, li = i - b*N_;
  if(li >= count[b]) return;
  float nv = ns[i];
  float bv = 10.f*nv;
  #pragma unroll
  for(int j=0;j<10;j++){
    int nb = nbr[(size_t)j*(2*N_)+i];
    if(nb>=0) bv += ns[nb];
  }
  nd[i] = sqrtf(nv*mc[i]/(bv+1e-12f));
}

// fused mfinal + x0 + A(x0) + r0/z0/p0 + rz0; writes coupled state st[2i]=(r,minv), st[2i+1]=(p,n)
__global__ __launch_bounds__(256) void k_Ar0(const int* count, const int* nbr, const float* n,
                      const float4* splat4, float4* meta4, float4* x4, float4* st,
                      double* rz0){
  int i = blockIdx.x*256 + threadIdx.x;
  int b = i / N_, li = i - b*N_;
  double a0=0.0,a1=0.0,a2=0.0;
  if(li < count[b]){
    float4 vb4 = splat4[i];
    float wsi = vb4.w;
    float nv = n[i];
    float x0 = vb4.x/(wsi+1e-12f);
    float x1 = vb4.y/(wsi+1e-12f);
    float x2 = vb4.z/(wsi+1e-12f);
    float bv = 10.f*nv;
    float s0=10.f*(nv*x0), s1=10.f*(nv*x1), s2=10.f*(nv*x2);
    #pragma unroll
    for(int j=0;j<10;j++){
      int nb = nbr[(size_t)j*(2*N_)+i];
      if(nb>=0){
        float4 vbn = splat4[nb];
        float nn = n[nb];
        bv += nn;
        s0 += nn*(vbn.x/(vbn.w+1e-12f));
        s1 += nn*(vbn.y/(vbn.w+1e-12f));
        s2 += nn*(vbn.z/(vbn.w+1e-12f));
      }
    }
    float mfin = nv*bv;
    float Ad = fmaxf(200.0f*(mfin - 10.f*nv*nv) + wsi, 1e-5f);
    float mi = 1.0f/Ad;
    float A0 = 200.f*(mfin*x0 - nv*s0) + wsi*x0;
    float A1 = 200.f*(mfin*x1 - nv*s1) + wsi*x1;
    float A2 = 200.f*(mfin*x2 - nv*s2) + wsi*x2;
    float r0v = vb4.x-A0, r1v = vb4.y-A1, r2v = vb4.z-A2;
    float z0=mi*r0v, z1=mi*r1v, z2=mi*r2v;
    meta4[i]=make_float4(nv,mfin,wsi,mi);
    x4[i]=make_float4(x0,x1,x2,0.f);
    st[2*(size_t)i]  =make_float4(r0v,r1v,r2v,mi);
    st[2*(size_t)i+1]=make_float4(z0,z1,z2,nv);
    a0=(double)r0v*z0; a1=(double)r1v*z1; a2=(double)r2v*z2;
  }
  a0=blockReduceD(a0); a1=blockReduceD(a1); a2=blockReduceD(a2);
  if(threadIdx.x==0){
    double* base = rz0 + b*RZB_;
    redAdd(base,0,a0); redAdd(base,1,a1); redAdd(base,2,a2);
  }
}

// fused p-update + A; coupled state: stOld[2nb]=(r,minv), stOld[2nb+1]=(p,n) -> ONE cache line
__global__ __launch_bounds__(256) void k_Ap(const int* count, const int* nbr, const float4* meta4,
                     const float4* stOld, float4* stNew, float4* Ap4,
                     const double* bNum, const double* bDen, int bstr, double* pAp){
  int i = blockIdx.x*256 + threadIdx.x;
  int b = i / N_, li = i - b*N_;
  double a0=0.0,a1=0.0,a2=0.0;
  const double* nB_ = bNum + b*bstr;
  const double* dB_ = bDen + b*bstr;
  float be0 = redSum(nB_,0) / (redSum(dB_,0)+1e-12f);
  float be1 = redSum(nB_,1) / (redSum(dB_,1)+1e-12f);
  float be2 = redSum(nB_,2) / (redSum(dB_,2)+1e-12f);
  if(li < count[b]){
    float4 mt = meta4[i];
    float nv = mt.x, mfin = mt.y, wsi = mt.z;
    float4 rs = stOld[2*(size_t)i];
    float4 ps = stOld[2*(size_t)i+1];
    float p0 = rs.w*rs.x + be0*ps.x;
    float p1 = rs.w*rs.y + be1*ps.y;
    float p2 = rs.w*rs.z + be2*ps.z;
    float s0=10.f*(nv*p0), s1=10.f*(nv*p1), s2=10.f*(nv*p2);
    #pragma unroll
    for(int j=0;j<10;j++){
      int nb = nbr[(size_t)j*(2*N_)+i];
      if(nb>=0){
        float4 rn = stOld[2*(size_t)nb];
        float4 pn = stOld[2*(size_t)nb+1];
        float nn = pn.w;
        s0 += nn*(rn.w*rn.x + be0*pn.x);
        s1 += nn*(rn.w*rn.y + be1*pn.y);
        s2 += nn*(rn.w*rn.z + be2*pn.z);
      }
    }
    float A0 = 200.f*(mfin*p0 - nv*s0) + wsi*p0;
    float A1 = 200.f*(mfin*p1 - nv*s1) + wsi*p1;
    float A2 = 200.f*(mfin*p2 - nv*s2) + wsi*p2;
    stNew[2*(size_t)i]  = rs;                        // carry r forward
    stNew[2*(size_t)i+1]= make_float4(p0,p1,p2,nv);
    Ap4[i]=make_float4(A0,A1,A2,0.f);
    a0=(double)p0*A0; a1=(double)p1*A1; a2=(double)p2*A2;
  }
  a0=blockReduceD(a0); a1=blockReduceD(a1); a2=blockReduceD(a2);
  if(threadIdx.x==0){
    double* base = pAp + b*PAPB_;
    redAdd(base,0,a0); redAdd(base,1,a1); redAdd(base,2,a2);
  }
}

// x += a p; r -= a Ap (in place on st: no one gathers r during upd1)
__global__ __launch_bounds__(256) void k_upd1(const int* count, float4* x4, float4* st,
                       const float4* Ap4,
                       const double* rzCur, const double* pApC, double* rzNew, int doRz){
  int i = blockIdx.x*256 + threadIdx.x;
  int b = i / N_, li = i - b*N_;
  double a0=0.0,a1=0.0,a2=0.0;
  const double* rc = rzCur + b*RZB_;
  const double* pc = pApC  + b*PAPB_;
  float al0 = redSum(rc,0) / (redSum(pc,0)+1e-12f);
  float al1 = redSum(rc,1) / (redSum(pc,1)+1e-12f);
  float al2 = redSum(rc,2) / (redSum(pc,2)+1e-12f);
  if(li < count[b]){
    float4 xv = x4[i];
    float4 rv = st[2*(size_t)i];
    float4 pv = st[2*(size_t)i+1];
    float4 av = Ap4[i];
    float mi = rv.w;
    float x0=xv.x+al0*pv.x, x1=xv.y+al1*pv.y, x2=xv.z+al2*pv.z;
    float r0v=rv.x-al0*av.x, r1v=rv.y-al1*av.y, r2v=rv.z-al2*av.z;
    float z0=mi*r0v, z1=mi*r1v, z2=mi*r2v;
    x4[i]=make_float4(x0,x1,x2,0.f);
    st[2*(size_t)i]=make_float4(r0v,r1v,r2v,mi);
    a0=(double)r0v*z0; a1=(double)r1v*z1; a2=(double)r2v*z2;
  }
  if(doRz){
    a0=blockReduceD(a0); a1=blockReduceD(a1); a2=blockReduceD(a2);
    if(threadIdx.x==0){
      double* base = rzNew + b*RZB_;
      redAdd(base,0,a0); redAdd(base,1,a1); redAdd(base,2,a2);
    }
  }
}

__global__ __launch_bounds__(256) void k_out(const float4* x4, const int* gpix, float* out){
  int idx = blockIdx.x*256 + threadIdx.x;   // grid exactly 2N/256
  int b = idx / N_, pix = idx % N_;
  float4 xv = x4[gpix[idx]];
  out[((size_t)(b*3+0))*N_+pix] = xv.x;
  out[((size_t)(b*3+1))*N_+pix] = xv.y;
  out[((size_t)(b*3+2))*N_+pix] = xv.z;
}

// ---------------- host launcher ----------------

extern "C" void kernel_launch(void* const* d_in, const int* in_sizes, int n_in,
                              void* d_out, int out_size, void* d_ws, size_t ws_size,
                              hipStream_t stream){
  const float* image=(const float*)d_in[0];
  const float* feature=(const float*)d_in[1];
  const float* pred=(const float*)d_in[2];
  const float* w1=(const float*)d_in[3];  const float* b1=(const float*)d_in[4];
  const float* g1=(const float*)d_in[5];  const float* be1=(const float*)d_in[6];
  const float* w2=(const float*)d_in[7];  const float* b2=(const float*)d_in[8];
  const float* g2=(const float*)d_in[9];  const float* be2=(const float*)d_in[10];
  const float* wd1=(const float*)d_in[11];const float* bd1=(const float*)d_in[12];
  const float* gd1=(const float*)d_in[13];const float* bed1=(const float*)d_in[14];
  const float* wd2=(const float*)d_in[15];const float* bd2=(const float*)d_in[16];
  const float* gd2=(const float*)d_in[17];const float* bed2=(const float*)d_in[18];
  const float* wf=(const float*)d_in[19]; const float* bf=(const float*)d_in[20];
  float* outp=(float*)d_out;                          // (B,3,H,W)
  float* confout = outp + (size_t)B_*3*N_;            // (B,1,H,W)

  char* wsb=(char*)d_ws;
  float* scal=(float*)wsb;                  // [0..1] imgmax, [2..3] featmax, [4] confmax
  int* count=(int*)(wsb+256);               // count[2]
  double* scalD=(double*)(wsb+4096);        // 12608 doubles (see layout defines)
  double* zeroD = scalD;
  auto rzArr  = [&](int it)->double*{ return scalD + RZ0_  + it*192; };   // batch stride RZB_
  auto pApArr = [&](int it)->double*{ return scalD + PAP0_ + it*192; };   // batch stride PAPB_
  auto gnAcc  = [&](int L)->double*{ return scalD + GN0_ + L*512; };
  float* wtT = (float*)(wsb + 131072);      // 12544 floats (transposed conv weights)
  float* wtT1 = wtT;      // conv1  (ICKK=96)
  float* wtT2 = wtT+1536; // conv2  (256)
  float* wtT3 = wtT+5632; // convd1 (144)
  float* wtT4 = wtT+7936; // wd2    (288)

  size_t off = 262144;
  auto alloc=[&](size_t bytes)->char*{ char* pp=wsb+off; off=(off+bytes+255)&~(size_t)255; return pp; };
  const size_t ALLOC0 = off;

  // CNN region (dead once conf is in confr; bilateral region overlaps it)
  float* x1   =(float*)alloc((size_t)B_*16*192*256*4);
  float* x2   =(float*)alloc((size_t)B_*16*96*128*4);
  float* dx1  =(float*)alloc((size_t)B_*16*96*128*4);
  float* dx1r =(float*)alloc((size_t)B_*16*192*256*4);
  float* dx2  =(float*)alloc((size_t)B_*16*192*256*4);
  float* dx2r =(float*)alloc((size_t)B_*16*N_*4);

  // bilateral region (reset offset: CNN buffers dead before the solver memsets/writes)
  off = ALLOC0;
  int*    winner =(int*)   alloc((size_t)2*T_*4);
  int2*   cidx2  =(int2*)  alloc((size_t)2*T_*8);
  int*    hpix   =(int*)   alloc((size_t)2*N_*4);    // becomes gpix after k_px3
  int2*   cpix2  =(int2*)  alloc((size_t)2*N_*8);
  int*    slot_of=(int*)   alloc((size_t)2*N_*4);
  int*    nbr    =(int*)   alloc((size_t)2*N_*10*4);
  float*  mcomp  =(float*) alloc((size_t)2*N_*4);    // mcomp..splatE contiguous: one memset
  float4* splat4 =(float4*)alloc((size_t)2*N_*16);
  float*  mcompE =(float*) alloc((size_t)2*N_*4);
  float*  splatE =(float*) alloc((size_t)2*N_*16);
  float*  nA     =(float*) alloc((size_t)2*N_*4);
  float*  nB     =(float*) alloc((size_t)2*N_*4);
  float4* meta4  =(float4*)alloc((size_t)2*N_*16);
  float4* x4     =(float4*)alloc((size_t)2*N_*16);
  float4* stA    =(float4*)alloc((size_t)2*N_*32);   // coupled (r,minv)+(p,n)
  float4* stB    =(float4*)alloc((size_t)2*N_*32);
  int*    bcnt   =(int*)   alloc((size_t)G2T_*4);
  int*    boff   =(int*)   alloc((size_t)G2T_*4);
  float4* Ap4    = splat4;        // alias: splat4 dead after k_Ar0
  float*  confr  = (float*)stB;   // alias: stB first written in k_Ap it=0, confr dead after px3

  dim3 blk(256), blk64(64);

  // ---- init scalars (scal, count, scalD) ----
  hipMemsetAsync(wsb, 0, 4096 + 12608*8, stream);

  // ---- CNN ----
  k_wt<<<49,blk,0,stream>>>(w1,w2,wd1,wd2,wtT);
  k_maxes<<<128,blk,0,stream>>>((const float4*)image,(const float4*)feature,scal);

  k_convT<true,false,false,3,3,4,2,true,384,512,192,256><<<(B_*96*256)/64,blk64,0,stream>>>(
      image,pred,wtT1,b1,x1,gnAcc(0),scal, nullptr,nullptr,nullptr, nullptr,nullptr,nullptr);
  k_convT<false,true,false,16,0,4,2,true,192,256,96,128><<<(B_*48*128)/64,blk64,0,stream>>>(
      x1,x1,wtT2,b2,x2,gnAcc(1),scal, gnAcc(0),g1,be1, nullptr,nullptr,nullptr);
  k_convT<false,true,false,16,0,3,1,false,96,128,96,128><<<(B_*48*128)/64,blk64,0,stream>>>(
      x2,x2,wtT3,bd1,dx1,gnAcc(2),scal, gnAcc(1),g2,be2, nullptr,nullptr,nullptr);
  k_resizeGN<<<(B_*16*192*256)/256,blk,0,stream>>>(dx1, dx1r, gnAcc(2), gd1, bed1, 96,128, 192,256);
  k_convT<false,false,true,16,16,3,1,false,192,256,192,256><<<(B_*96*256)/64,blk64,0,stream>>>(
      dx1r,x1,wtT4,bd2,dx2,gnAcc(3),scal, nullptr,nullptr,nullptr, gnAcc(0),g1,be1);
  k_resizeGN<<<(B_*16*N_)/256,blk,0,stream>>>(dx2, dx2r, gnAcc(3), gd2, bed2, 192,256, 384,512);

  k_conv5<<<(B_*(N_/2))/256,blk,0,stream>>>(dx2r, wf, bf, confr, scal);

  // ---- bilateral solver setup ----
  hipMemsetAsync(winner, 0xFF, (size_t)2*T_*4, stream);                      // winner = -1
  hipMemsetAsync(cidx2,  0xFF, (size_t)2*T_*8, stream);                      // .y=-1 = unoccupied
  hipMemsetAsync(mcomp,  0,    (size_t)2*N_*40, stream);                     // mcomp+splat4+mcompE+splatE
  k_px1<<<G2N_,blk,0,stream>>>(feature,scal,hpix,cpix2,winner);
  k_cnt<<<G2T_,blk,0,stream>>>(winner,bcnt);
  k_scan<<<1,blk,0,stream>>>(bcnt,boff,count);
  k_cmp<<<G2T_,blk,0,stream>>>(winner,boff,cidx2,slot_of);
  k_px3<<<G2N_,blk,0,stream>>>(hpix,cidx2,confr,scal,confout,pred,mcomp,splat4,mcompE,splatE);

  // ---- bistochastization: fused extras-merge + nbr-build + it0, then 9 more ----
  k_bisto0<<<G2N_,blk,0,stream>>>(count,slot_of,cpix2,cidx2,nbr,mcomp,mcompE,splat4,(const float4*)splatE,nA);
  for(int it=1; it<10; ++it){
    float* src = (it&1) ? nA : nB;
    float* dst = (it&1) ? nB : nA;
    k_bisto<<<G2N_,blk,0,stream>>>(count,nbr,src,dst,mcomp);
  }
  float* nfin = nB;   // it9 (odd) wrote nB

  k_Ar0<<<G2N_,blk,0,stream>>>(count,nbr,nfin,splat4,meta4,x4,stA,rzArr(0));

  float4* stb[2]={stA,stB};
  for(int it=0; it<12; ++it){
    const double* bN = (it==0) ? zeroD : rzArr(it);
    const double* bD = (it==0) ? zeroD : rzArr(it-1);
    int bstr = (it==0) ? 0 : RZB_;
    k_Ap<<<G2N_,blk,0,stream>>>(count,nbr,meta4,stb[it&1],stb[(it+1)&1],Ap4,bN,bD,bstr,pApArr(it));
    k_upd1<<<G2N_,blk,0,stream>>>(count,x4,stb[(it+1)&1],Ap4,rzArr(it),pApArr(it),rzArr(it+1),(it<11)?1:0);
  }
  k_out<<<G2N_,blk,0,stream>>>(x4,hpix,outp);

  (void)in_sizes; (void)n_in; (void)out_size; (void)ws_size;
}

// Round 14
// 897.428 us; speedup vs baseline: 1.1051x; 1.1051x over previous
//
#include <hip/hip_runtime.h>

#define H_ 384
#define W_ 512
#define N_ (H_*W_)        // 196608
#define B_ 2
#define T_ 1048576
#define TMASK_ 0xFFFFFu
#define G2N_ ((2*N_)/256) // 1536
#define G2T_ ((2*T_)/256) // 8192
#define CHS_ 64           // doubles per channel accumulator block (8 subs x 8-double spacing)
// scalD layout (doubles), all accumulators 8-way sub-slot spread (64B apart):
//   [0..191]   zeroD (stays 0; beta num/den at it==0)
//   rz  [b][it] at 192   + b*2688 + it*192   (it=0..13)
//   pAp [b][it] at 5568  + b*2496 + it*192   (it=0..12)
//   GN acc      at 10560 + L*512 + bg*128 (+j*8 sum, +64+j*8 sumsq)
#define RZ0_ 192
#define RZB_ 2688
#define PAP0_ 5568
#define PAPB_ 2496
#define GN0_ 10560

__device__ __forceinline__ int prime(int d){
  switch(d){
    case 0: return 73856093;
    case 1: return 19349663;
    case 2: return 83492791;
    case 3: return 49979687;
    default: return 24036583;
  }
}

__device__ __forceinline__ float clampScale(float s){ return fminf(fmaxf(s,1e-5f),1.0f); }

__device__ __forceinline__ double blockReduceD(double v){
  __shared__ double sh[4];
  for(int s=32;s>0;s>>=1) v += __shfl_down(v,s,64);
  int lane=threadIdx.x&63, w=threadIdx.x>>6;
  if(lane==0) sh[w]=v;
  __syncthreads();
  double r = sh[0]+sh[1]+sh[2]+sh[3];
  __syncthreads();
  return r;
}
__device__ __forceinline__ float blockReduceMaxF(float v){
  __shared__ float sh[4];
  for(int s=32;s>0;s>>=1) v = fmaxf(v,__shfl_down(v,s,64));
  int lane=threadIdx.x&63, w=threadIdx.x>>6;
  if(lane==0) sh[w]=v;
  __syncthreads();
  float r = fmaxf(fmaxf(sh[0],sh[1]),fmaxf(sh[2],sh[3]));
  __syncthreads();
  return r;
}

// spread atomic into 8 sub-slots (separate 64B lines); consumer sums 8
__device__ __forceinline__ void redAdd(double* base, int c, double v){
  atomicAdd(&base[c*CHS_ + ((blockIdx.x&7)<<3)], v);
}
__device__ __forceinline__ float redSum(const double* base, int c){
  double s=0.0;
  #pragma unroll
  for(int j=0;j<8;j++) s += base[c*CHS_ + j*8];
  return (float)s;
}

// ---------------- CNN kernels ----------------

__global__ __launch_bounds__(256) void k_maxes(const float4* img4, const float4* feat4, float* scal){
  const int PB = (3*N_)/4;
  for(int b=0;b<2;b++){
    float lm=0.f, lf=0.f;
    for(int idx = blockIdx.x*256+threadIdx.x; idx<PB; idx += gridDim.x*256){
      float4 a=img4[(size_t)b*PB+idx], c=feat4[(size_t)b*PB+idx];
      lm=fmaxf(lm, fmaxf(fmaxf(a.x,a.y),fmaxf(a.z,a.w)));
      lf=fmaxf(lf, fmaxf(fmaxf(c.x,c.y),fmaxf(c.z,c.w)));
    }
    lm=blockReduceMaxF(lm); lf=blockReduceMaxF(lf);
    if(threadIdx.x==0){
      atomicMax((int*)&scal[b],   __float_as_int(lm));
      atomicMax((int*)&scal[2+b], __float_as_int(lf));
    }
  }
}

template<bool SCALEA,bool GN,int NCH,int IC,int K,int S,bool EDGE,int IH,int IW>
__device__ __forceinline__ void conv_accum(const float* __restrict__ plane0, int icBase, float sA,
                                           int oy, int ox, const float* wlds, float acc[16],
                                           const float* gmf, const float* grs,
                                           const float* ggm, const float* gbt){
  for(int ic=0; ic<NCH; ic++){
    const float* plane = plane0 + (size_t)ic*IH*IW;
    float mf=0.f, rs=0.f, gm=0.f, bt=0.f;
    if(GN){ mf=gmf[ic]; rs=grs[ic]; gm=ggm[ic]; bt=gbt[ic]; }
    #pragma unroll
    for(int ky=0;ky<K;ky++){
      int iy = oy*S + ky - 1;
      int cy = min(max(iy,0),IH-1);
      bool yin = (iy>=0)&&(iy<IH);
      const float* row = plane + cy*IW;
      #pragma unroll
      for(int kx=0;kx<K;kx++){
        int ix = ox*S + kx - 1;
        float v;
        if(EDGE){
          int cx = min(max(ix,0),IW-1);
          v = row[cx];
          if(SCALEA) v = v / sA;
          if(GN)     v = fmaxf((v-mf)*rs*gm+bt, 0.f);
        } else {
          bool inb = yin && ix>=0 && ix<IW;
          if(inb){
            v = row[ix];
            if(SCALEA) v = v / sA;
            if(GN)     v = fmaxf((v-mf)*rs*gm+bt, 0.f);
          } else v = 0.f;
        }
        const float4* wp = (const float4*)&wlds[(((icBase+ic)*K+ky)*K+kx)*16];
        #pragma unroll
        for(int q=0;q<4;q++){
          float4 w4 = wp[q];
          acc[4*q+0] += v*w4.x;
          acc[4*q+1] += v*w4.y;
          acc[4*q+2] += v*w4.z;
          acc[4*q+3] += v*w4.w;
        }
      }
    }
  }
}

template<bool SCALEA,bool GNA,bool GNB,int ICA,int ICB,int K,int S,bool EDGE,int IH,int IW,int OH,int OW>
__global__ __launch_bounds__(256) void k_convT(const float* __restrict__ inA, const float* __restrict__ inB,
                        const float* __restrict__ wt, const float* __restrict__ bias,
                        float* __restrict__ out, double* gnaccOut, const float* scal,
                        const double* accA, const float* gA, const float* bA,
                        const double* accB, const float* gB, const float* bB){
  constexpr int IC = ICA+ICB;
  __shared__ float wlds[IC*K*K*16];
  __shared__ float blds[16];
  __shared__ float gnA_mf[16], gnA_rs[16], gnA_gm[16], gnA_bt[16];
  __shared__ float gnB_mf[16], gnB_rs[16], gnB_gm[16], gnB_bt[16];
  for(int i=threadIdx.x; i<IC*K*K*16; i+=256){
    int oc=i&15, ickk=i>>4;
    wlds[i] = wt[oc*IC*K*K + ickk];
  }
  int idx = blockIdx.x*256+threadIdx.x;      // grid exactly B*OH*OW/256
  int ox = idx % OW; int t=idx/OW; int oy=t%OH; int b=t/OH;
  if(threadIdx.x<16){
    int c = threadIdx.x;
    blds[c]=bias[c];
    double len = 8.0*(double)(IH*IW);
    if(GNA){
      const double* ba = accA + (b*2 + (c>>3))*128;
      double s=0.0,s2=0.0;
      #pragma unroll
      for(int j=0;j<8;j++){ s+=ba[j*8]; s2+=ba[64+j*8]; }
      double mean = s/len; double var = s2/len - mean*mean;
      gnA_rs[c] = (float)(1.0/sqrt(var + 1e-5));
      gnA_mf[c] = (float)mean;
      gnA_gm[c] = gA[c]; gnA_bt[c] = bA[c];
    }
    if(GNB){
      const double* bb = accB + (b*2 + (c>>3))*128;
      double s=0.0,s2=0.0;
      #pragma unroll
      for(int j=0;j<8;j++){ s+=bb[j*8]; s2+=bb[64+j*8]; }
      double mean = s/len; double var = s2/len - mean*mean;
      gnB_rs[c] = (float)(1.0/sqrt(var + 1e-5));
      gnB_mf[c] = (float)mean;
      gnB_gm[c] = gB[c]; gnB_bt[c] = bB[c];
    }
  }
  __syncthreads();
  float sA = SCALEA ? clampScale(scal[b]) : 1.0f;
  float acc[16];
  #pragma unroll
  for(int oc=0;oc<16;oc++) acc[oc]=0.f;
  conv_accum<SCALEA,GNA,ICA,IC,K,S,EDGE,IH,IW>(inA + (size_t)b*ICA*IH*IW, 0, sA, oy, ox, wlds, acc,
                                               gnA_mf,gnA_rs,gnA_gm,gnA_bt);
  if(ICB>0)
    conv_accum<false,GNB,(ICB>0?ICB:1),IC,K,S,EDGE,IH,IW>(inB + (size_t)b*ICB*IH*IW, ICA, 1.0f, oy, ox, wlds, acc,
                                               gnB_mf,gnB_rs,gnB_gm,gnB_bt);
  double sl=0.0,s2l=0.0,sh=0.0,s2h=0.0;
  #pragma unroll
  for(int oc=0;oc<16;oc++){
    float vv = acc[oc] + blds[oc];
    out[(((size_t)b*16+oc)*OH+oy)*OW+ox] = vv;
    if(oc<8){ sl += vv; s2l += (double)vv*(double)vv; }
    else    { sh += vv; s2h += (double)vv*(double)vv; }
  }
  sl=blockReduceD(sl); s2l=blockReduceD(s2l);
  sh=blockReduceD(sh); s2h=blockReduceD(s2h);
  if(threadIdx.x==0){
    int sub = (blockIdx.x&7)<<3;
    atomicAdd(&gnaccOut[(b*2+0)*128 + sub],      sl);
    atomicAdd(&gnaccOut[(b*2+0)*128 + 64 + sub], s2l);
    atomicAdd(&gnaccOut[(b*2+1)*128 + sub],      sh);
    atomicAdd(&gnaccOut[(b*2+1)*128 + 64 + sub], s2h);
  }
}

// fused GN(+relu) applied per tap, then half-pixel bilinear resize (edge clamp)
__global__ __launch_bounds__(256) void k_resizeGN(const float* in, float* out, const double* acc,
                                                  const float* gamma, const float* beta,
                                                  int IH, int IW, int OH, int OW){
  int idx = blockIdx.x*256 + threadIdx.x;
  int total = B_*16*OH*OW;
  if(idx>=total) return;
  int ox = idx%OW; int t=idx/OW; int oy=t%OH; t/=OH;   // t = b*16+c
  int c = t%16, b = t/16;
  const double* ba = acc + (b*2 + (c>>3))*128;
  double s=0.0,s2=0.0;
  #pragma unroll
  for(int j=0;j<8;j++){ s+=ba[j*8]; s2+=ba[64+j*8]; }
  double len = 8.0*(double)(IH*IW);
  double mean = s/len;
  double var = s2/len - mean*mean;
  float rstd = (float)(1.0/sqrt(var + 1e-5));
  float mf = (float)mean;
  float g = gamma[c], be = beta[c];
  const float* plane = in + (size_t)t*IH*IW;
  float sy = (float)IH/(float)OH, sx=(float)IW/(float)OW;
  float fy = (oy+0.5f)*sy-0.5f, fx=(ox+0.5f)*sx-0.5f;
  float fy0 = floorf(fy), fx0=floorf(fx);
  float ty = fy-fy0, tx = fx-fx0;
  int y0 = min(max((int)fy0,0),IH-1), y1 = min(max((int)fy0+1,0),IH-1);
  int x0 = min(max((int)fx0,0),IW-1), x1 = min(max((int)fx0+1,0),IW-1);
  float v00=fmaxf((plane[y0*IW+x0]-mf)*rstd*g+be,0.f);
  float v01=fmaxf((plane[y0*IW+x1]-mf)*rstd*g+be,0.f);
  float v10=fmaxf((plane[y1*IW+x0]-mf)*rstd*g+be,0.f);
  float v11=fmaxf((plane[y1*IW+x1]-mf)*rstd*g+be,0.f);
  out[idx] = (1.f-ty)*((1.f-tx)*v00+tx*v01) + ty*((1.f-tx)*v10+tx*v11);
}

// conf head: TWO y-adjacent pixels per thread (shares input rows)
__global__ __launch_bounds__(256) void k_conv5(const float* in, const float* wf, const float* bf,
                                               float* confr, float* scal){
  int idx = blockIdx.x*256 + threadIdx.x;   // grid exactly B*(N/2)/256
  int ph = idx % (N_/2); int b = idx / (N_/2);
  int oyh = ph / W_, ox = ph % W_;
  int oy0 = oyh*2;
  float acc0 = bf[0], acc1 = bf[0];
  for(int ic=0; ic<16; ic++){
    const float* plane = in + ((size_t)b*16+ic)*N_;
    #pragma unroll
    for(int ky=0;ky<3;ky++){
      int iy0 = min(max(oy0+ky-1,0),H_-1);
      int iy1 = min(max(oy0+ky,0),H_-1);
      const float* row0 = plane + iy0*W_;
      const float* row1 = plane + iy1*W_;
      #pragma unroll
      for(int kx=0;kx<3;kx++){
        int ix = min(max(ox+kx-1,0),W_-1);
        float w = wf[(ic*3+ky)*3+kx];
        acc0 += row0[ix]*w;
        acc1 += row1[ix]*w;
      }
    }
  }
  float c0 = 0.5f*(tanhf(acc0)+1.0f);
  float c1 = 0.5f*(tanhf(acc1)+1.0f);
  confr[(size_t)b*N_ + oy0*W_ + ox]     = c0;
  confr[(size_t)b*N_ + (oy0+1)*W_ + ox] = c1;
  float mx = blockReduceMaxF(fmaxf(c0,c1));
  if(threadIdx.x==0) atomicMax((int*)&scal[4], __float_as_int(mx));
}

// ---------------- bilateral solver setup (both batches merged) ----------------

__global__ __launch_bounds__(256) void k_px1(const float* feat, const float* scal,
                                             int* hpix, int2* cpix2, int* winner){
  int idx = blockIdx.x*256 + threadIdx.x;   // grid exactly 2N/256
  int b = idx / N_, pix = idx % N_;
  int y = pix / W_, x = pix % W_;
  float sF = clampScale(scal[2+b]);
  const float* fb = feat + (size_t)b*3*N_;
  // exact reference eval order, no FMA contraction (coords are integer-binned)
  float R  = __fmul_rn(__fdiv_rn(fb[pix],      sF), 255.0f);
  float G  = __fmul_rn(__fdiv_rn(fb[N_+pix],   sF), 255.0f);
  float Bl = __fmul_rn(__fdiv_rn(fb[2*N_+pix], sF), 255.0f);
  float Y = __fadd_rn(__fadd_rn(__fadd_rn(__fmul_rn(0.299f,R),     __fmul_rn(0.587f,G)),  __fmul_rn(0.114f,Bl)), 0.0f);
  float U = __fadd_rn(__fadd_rn(__fadd_rn(__fmul_rn(-0.168736f,R), __fmul_rn(-0.331264f,G)), __fmul_rn(0.5f,Bl)), 128.0f);
  float V = __fadd_rn(__fadd_rn(__fadd_rn(__fmul_rn(0.5f,R),       __fmul_rn(-0.418688f,G)), __fmul_rn(-0.081312f,Bl)), 128.0f);
  int c[5];
  c[0] = (int)floorf(__fdiv_rn((float)x, 7.0f));
  c[1] = (int)floorf(__fdiv_rn((float)y, 7.0f));
  c[2] = (int)floorf(__fdiv_rn(Y, 8.0f));
  c[3] = (int)floorf(__fdiv_rn(U, 2.0f));
  c[4] = (int)floorf(__fdiv_rn(V, 2.0f));
  unsigned hh = 0;
  #pragma unroll
  for(int d=0;d<5;d++) hh += (unsigned)c[d]*(unsigned)prime(d);
  hh &= TMASK_;
  hpix[idx]=(int)hh;
  cpix2[idx]=make_int2(c[0] | (c[1]<<10) | (c[2]<<20), c[3] | (c[4]<<10));
  atomicMax(&winner[(size_t)b*T_+(int)hh], pix);   // last-writer (max pix) wins = XLA scatter
}

// --- atomic-free 3-phase compaction ---

__global__ __launch_bounds__(256) void k_cnt(const int* winner, int* bcnt){
  int t = blockIdx.x*256 + threadIdx.x;   // grid exactly 2T/256
  bool occ = winner[t] >= 0;
  __shared__ int wc[4];
  unsigned long long mk = __ballot(occ);
  int lane = threadIdx.x & 63, w = threadIdx.x >> 6;
  if(lane==0) wc[w] = __popcll(mk);
  __syncthreads();
  if(threadIdx.x==0) bcnt[blockIdx.x] = wc[0]+wc[1]+wc[2]+wc[3];
}

__global__ __launch_bounds__(256) void k_scan(const int* bcnt, int* boff, int* count){
  __shared__ int sh[256];
  __shared__ int carry;
  if(threadIdx.x==0) carry=0;
  __syncthreads();
  for(int chunk=0; chunk<32; ++chunk){
    if(chunk==16){
      if(threadIdx.x==0){ count[0]=carry; carry=0; }
      __syncthreads();
    }
    int v = bcnt[chunk*256+threadIdx.x];
    sh[threadIdx.x]=v;
    __syncthreads();
    for(int s2=1;s2<256;s2<<=1){
      int add = (threadIdx.x>=s2)? sh[threadIdx.x-s2] : 0;
      __syncthreads();
      sh[threadIdx.x]+=add;
      __syncthreads();
    }
    int incl = sh[threadIdx.x];
    boff[chunk*256+threadIdx.x] = carry + incl - v;
    __syncthreads();
    if(threadIdx.x==255) carry += incl;
    __syncthreads();
  }
  if(threadIdx.x==0) count[1]=carry;
}

__global__ __launch_bounds__(256) void k_cmp(const int* winner, const int* boff,
                                             int2* cidx2, int* slot_of){
  int t = blockIdx.x*256 + threadIdx.x;   // grid exactly 2T/256
  int b = t / T_;
  int wn = winner[t];
  bool occ = wn >= 0;
  __shared__ int wc[4];
  unsigned long long mk = __ballot(occ);
  int lane = threadIdx.x & 63, w = threadIdx.x >> 6;
  if(lane==0) wc[w] = __popcll(mk);
  __syncthreads();
  int wpre = 0;
  for(int k2=0;k2<4;k2++) if(k2<w) wpre += wc[k2];
  if(occ){
    int li = boff[blockIdx.x] + wpre + __popcll(mk & ((1ull<<lane)-1ull));
    int gi = b*N_ + li;
    cidx2[t] = make_int2(gi, wn);
    slot_of[gi] = t - b*T_;    // local slot hh
  }
}

// conf normalize + splat: winner plain-stores; non-winners (~10%) atomicAdd into extras
__global__ __launch_bounds__(256) void k_px3(int* hpix_gpix, const int2* cidx2, const float* confr,
                                             const float* scal, float* confout, const float* pred,
                                             float* mcomp, float4* splat4, float* mcompE, float* splatE){
  int idx = blockIdx.x*256 + threadIdx.x;   // grid exactly 2N/256
  int b = idx / N_, pix = idx % N_;
  int2 cw = cidx2[(size_t)b*T_ + hpix_gpix[idx]];
  int gi = cw.x;
  hpix_gpix[idx] = gi;
  float w = confr[idx] / fmaxf(scal[4], 1e-5f);
  confout[idx] = w;
  const float* pb = pred + (size_t)b*3*N_;
  float v0 = __fmul_rn(w, pb[pix]);
  float v1 = __fmul_rn(w, pb[N_+pix]);
  float v2 = __fmul_rn(w, pb[2*N_+pix]);
  if(cw.y == pix){
    splat4[gi] = make_float4(v0,v1,v2,w);
    mcomp[gi] = 1.0f;
  } else {
    float* s = splatE + 4*(size_t)gi;
    atomicAdd(s+0, v0);
    atomicAdd(s+1, v1);
    atomicAdd(s+2, v2);
    atomicAdd(s+3, w);
    atomicAdd(&mcompE[gi], 1.0f);
  }
}

// fused: merge extras + neighbor-table build + first bisto iter (n0=1)
__global__ __launch_bounds__(256) void k_bisto0(const int* count, const int* slot_of,
                      const int2* cpix2, const int2* cidx2, int* nbr,
                      float* mcomp, const float* mcompE, float4* splat4, const float4* splatE4,
                      float* nd){
  int i = blockIdx.x*256 + threadIdx.x;     // grid exactly 2N/256
  int b = i / N_, li = i - b*N_;
  if(li >= count[b]) return;
  int hh = slot_of[i];
  const int2* c2b = cidx2 + (size_t)b*T_;
  int2 cself = c2b[hh];
  int2 cp = cpix2[(size_t)b*N_ + cself.y];
  float4 sp = splat4[i]; float4 se = splatE4[i];
  sp.x+=se.x; sp.y+=se.y; sp.z+=se.z; sp.w+=se.w;
  splat4[i]=sp;
  float mTot = mcomp[i] + mcompE[i];
  mcomp[i]=mTot;
  float bv = 10.f;                          // 10*n with n=1
  #pragma unroll
  for(int j=0;j<10;j++){
    int d=j>>1; int off=(j&1)?1:-1;
    unsigned nh = ((unsigned)hh + (unsigned)(off*prime(d))) & TMASK_;
    int nb = -1;
    int2 cn2 = c2b[nh];
    if(cn2.y>=0){
      int2 cn = cpix2[(size_t)b*N_ + cn2.y];
      int e0 = cp.x + (d==0?off: d==1?off*(1<<10) : d==2?off*(1<<20) : 0);
      int e1 = cp.y + (d==3?off: d==4?off*(1<<10) : 0);
      if(cn.x==e0 && cn.y==e1) nb = cn2.x;
    }
    nbr[(size_t)j*(2*N_)+i]=nb;
    if(nb>=0) bv += 1.0f;                   // neighbor n = 1
  }
  nd[i] = sqrtf(1.0f*mTot/(bv+1e-12f));
}

__global__ __launch_bounds__(256) void k_bisto(const int* count, const int* nbr,
                                               const float* ns, float* nd, const float* mc){
  int i = blockIdx.x*256 + threadIdx.x;
  int b = i / N_, li = i - b*N_;
  if(li >= count[b]) return;
  float nv = ns[i];
  float bv = 10.f*nv;
  #pragma unroll
  for(int j=0;j<10;j++){
    int nb = nbr[(size_t)j*(2*N_)+i];
    if(nb>=0) bv += ns[nb];
  }
  nd[i] = sqrtf(nv*mc[i]/(bv+1e-12f));
}

// fused mfinal + x0 + A(x0) + r0/z0/p0 + rz0 per-batch reduction
__global__ __launch_bounds__(256) void k_Ar0(const int* count, const int* nbr, const float* n,
                      const float4* splat4, float4* meta4, float4* x4, float4* r4, float4* p4,
                      double* rz0){
  int i = blockIdx.x*256 + threadIdx.x;
  int b = i / N_, li = i - b*N_;
  double a0=0.0,a1=0.0,a2=0.0;
  if(li < count[b]){
    float4 vb4 = splat4[i];
    float wsi = vb4.w;
    float nv = n[i];
    float x0 = vb4.x/(wsi+1e-12f);
    float x1 = vb4.y/(wsi+1e-12f);
    float x2 = vb4.z/(wsi+1e-12f);
    float bv = 10.f*nv;
    float s0=10.f*(nv*x0), s1=10.f*(nv*x1), s2=10.f*(nv*x2);
    #pragma unroll
    for(int j=0;j<10;j++){
      int nb = nbr[(size_t)j*(2*N_)+i];
      if(nb>=0){
        float4 vbn = splat4[nb];
        float nn = n[nb];
        bv += nn;
        s0 += nn*(vbn.x/(vbn.w+1e-12f));
        s1 += nn*(vbn.y/(vbn.w+1e-12f));
        s2 += nn*(vbn.z/(vbn.w+1e-12f));
      }
    }
    float mfin = nv*bv;
    float Ad = fmaxf(200.0f*(mfin - 10.f*nv*nv) + wsi, 1e-5f);
    float mi = 1.0f/Ad;
    float A0 = 200.f*(mfin*x0 - nv*s0) + wsi*x0;
    float A1 = 200.f*(mfin*x1 - nv*s1) + wsi*x1;
    float A2 = 200.f*(mfin*x2 - nv*s2) + wsi*x2;
    float r0v = vb4.x-A0, r1v = vb4.y-A1, r2v = vb4.z-A2;
    float z0=mi*r0v, z1=mi*r1v, z2=mi*r2v;
    meta4[i]=make_float4(nv,mfin,wsi,mi);
    x4[i]=make_float4(x0,x1,x2,0.f);
    r4[i]=make_float4(r0v,r1v,r2v,mi);
    p4[i]=make_float4(z0,z1,z2,nv);
    a0=(double)r0v*z0; a1=(double)r1v*z1; a2=(double)r2v*z2;
  }
  a0=blockReduceD(a0); a1=blockReduceD(a1); a2=blockReduceD(a2);
  if(threadIdx.x==0){
    double* base = rz0 + b*RZB_;
    redAdd(base,0,a0); redAdd(base,1,a1); redAdd(base,2,a2);
  }
}

// fused p-update + A: p = minv*r + beta*pOld (self & neighbors on the fly), Ap=A(p), p.Ap reduce
__global__ __launch_bounds__(256) void k_Ap(const int* count, const int* nbr, const float4* meta4,
                     const float4* r4, const float4* pOld4, float4* pNew4, float4* Ap4,
                     const double* bNum, const double* bDen, int bstr, double* pAp){
  int i = blockIdx.x*256 + threadIdx.x;
  int b = i / N_, li = i - b*N_;
  double a0=0.0,a1=0.0,a2=0.0;
  const double* nB_ = bNum + b*bstr;
  const double* dB_ = bDen + b*bstr;
  float be0 = redSum(nB_,0) / (redSum(dB_,0)+1e-12f);
  float be1 = redSum(nB_,1) / (redSum(dB_,1)+1e-12f);
  float be2 = redSum(nB_,2) / (redSum(dB_,2)+1e-12f);
  if(li < count[b]){
    float4 mt = meta4[i];
    float nv = mt.x, mfin = mt.y, wsi = mt.z;
    float4 rs = r4[i];
    float4 ps = pOld4[i];
    float p0 = rs.w*rs.x + be0*ps.x;
    float p1 = rs.w*rs.y + be1*ps.y;
    float p2 = rs.w*rs.z + be2*ps.z;
    float s0=10.f*(nv*p0), s1=10.f*(nv*p1), s2=10.f*(nv*p2);
    #pragma unroll
    for(int j=0;j<10;j++){
      int nb = nbr[(size_t)j*(2*N_)+i];
      if(nb>=0){
        float4 rn = r4[nb];
        float4 pn = pOld4[nb];
        float nn = pn.w;
        s0 += nn*(rn.w*rn.x + be0*pn.x);
        s1 += nn*(rn.w*rn.y + be1*pn.y);
        s2 += nn*(rn.w*rn.z + be2*pn.z);
      }
    }
    float A0 = 200.f*(mfin*p0 - nv*s0) + wsi*p0;
    float A1 = 200.f*(mfin*p1 - nv*s1) + wsi*p1;
    float A2 = 200.f*(mfin*p2 - nv*s2) + wsi*p2;
    pNew4[i]=make_float4(p0,p1,p2,nv);
    Ap4[i]=make_float4(A0,A1,A2,0.f);
    a0=(double)p0*A0; a1=(double)p1*A1; a2=(double)p2*A2;
  }
  a0=blockReduceD(a0); a1=blockReduceD(a1); a2=blockReduceD(a2);
  if(threadIdx.x==0){
    double* base = pAp + b*PAPB_;
    redAdd(base,0,a0); redAdd(base,1,a1); redAdd(base,2,a2);
  }
}

__global__ __launch_bounds__(256) void k_upd1(const int* count, float4* x4, float4* r4,
                       const float4* p4, const float4* Ap4,
                       const double* rzCur, const double* pApC, double* rzNew, int doRz){
  int i = blockIdx.x*256 + threadIdx.x;
  int b = i / N_, li = i - b*N_;
  double a0=0.0,a1=0.0,a2=0.0;
  const double* rc = rzCur + b*RZB_;
  const double* pc = pApC  + b*PAPB_;
  float al0 = redSum(rc,0) / (redSum(pc,0)+1e-12f);
  float al1 = redSum(rc,1) / (redSum(pc,1)+1e-12f);
  float al2 = redSum(rc,2) / (redSum(pc,2)+1e-12f);
  if(li < count[b]){
    float4 xv = x4[i];
    float4 rv = r4[i];
    float4 pv = p4[i];
    float4 av = Ap4[i];
    float mi = rv.w;
    float x0=xv.x+al0*pv.x, x1=xv.y+al1*pv.y, x2=xv.z+al2*pv.z;
    float r0v=rv.x-al0*av.x, r1v=rv.y-al1*av.y, r2v=rv.z-al2*av.z;
    float z0=mi*r0v, z1=mi*r1v, z2=mi*r2v;
    x4[i]=make_float4(x0,x1,x2,0.f);
    r4[i]=make_float4(r0v,r1v,r2v,mi);
    a0=(double)r0v*z0; a1=(double)r1v*z1; a2=(double)r2v*z2;
  }
  if(doRz){
    a0=blockReduceD(a0); a1=blockReduceD(a1); a2=blockReduceD(a2);
    if(threadIdx.x==0){
      double* base = rzNew + b*RZB_;
      redAdd(base,0,a0); redAdd(base,1,a1); redAdd(base,2,a2);
    }
  }
}

__global__ __launch_bounds__(256) void k_out(const float4* x4, const int* gpix, float* out){
  int idx = blockIdx.x*256 + threadIdx.x;   // grid exactly 2N/256
  int b = idx / N_, pix = idx % N_;
  float4 xv = x4[gpix[idx]];
  out[((size_t)(b*3+0))*N_+pix] = xv.x;
  out[((size_t)(b*3+1))*N_+pix] = xv.y;
  out[((size_t)(b*3+2))*N_+pix] = xv.z;
}

// ---------------- host launcher ----------------

extern "C" void kernel_launch(void* const* d_in, const int* in_sizes, int n_in,
                              void* d_out, int out_size, void* d_ws, size_t ws_size,
                              hipStream_t stream){
  const float* image=(const float*)d_in[0];
  const float* feature=(const float*)d_in[1];
  const float* pred=(const float*)d_in[2];
  const float* w1=(const float*)d_in[3];  const float* b1=(const float*)d_in[4];
  const float* g1=(const float*)d_in[5];  const float* be1=(const float*)d_in[6];
  const float* w2=(const float*)d_in[7];  const float* b2=(const float*)d_in[8];
  const float* g2=(const float*)d_in[9];  const float* be2=(const float*)d_in[10];
  const float* wd1=(const float*)d_in[11];const float* bd1=(const float*)d_in[12];
  const float* gd1=(const float*)d_in[13];const float* bed1=(const float*)d_in[14];
  const float* wd2=(const float*)d_in[15];const float* bd2=(const float*)d_in[16];
  const float* gd2=(const float*)d_in[17];const float* bed2=(const float*)d_in[18];
  const float* wf=(const float*)d_in[19]; const float* bf=(const float*)d_in[20];
  float* outp=(float*)d_out;                          // (B,3,H,W)
  float* confout = outp + (size_t)B_*3*N_;            // (B,1,H,W)

  char* wsb=(char*)d_ws;
  float* scal=(float*)wsb;                  // [0..1] imgmax, [2..3] featmax, [4] confmax
  int* count=(int*)(wsb+256);               // count[2]
  double* scalD=(double*)(wsb+4096);        // 12608 doubles (see layout defines)
  double* zeroD = scalD;
  auto rzArr  = [&](int it)->double*{ return scalD + RZ0_  + it*192; };   // batch stride RZB_
  auto pApArr = [&](int it)->double*{ return scalD + PAP0_ + it*192; };   // batch stride PAPB_
  auto gnAcc  = [&](int L)->double*{ return scalD + GN0_ + L*512; };

  size_t off = 131072;
  auto alloc=[&](size_t bytes)->char*{ char* pp=wsb+off; off=(off+bytes+255)&~(size_t)255; return pp; };
  const size_t ALLOC0 = off;

  // CNN region (dead once conf is in confr; bilateral region overlaps it)
  float* x1   =(float*)alloc((size_t)B_*16*192*256*4);
  float* x2   =(float*)alloc((size_t)B_*16*96*128*4);
  float* dx1  =(float*)alloc((size_t)B_*16*96*128*4);
  float* dx1r =(float*)alloc((size_t)B_*16*192*256*4);
  float* dx2  =(float*)alloc((size_t)B_*16*192*256*4);
  float* dx2r =(float*)alloc((size_t)B_*16*N_*4);

  // bilateral region (reset offset: CNN buffers dead before the solver memsets/writes)
  off = ALLOC0;
  int*    winner =(int*)   alloc((size_t)2*T_*4);
  int2*   cidx2  =(int2*)  alloc((size_t)2*T_*8);
  int*    hpix   =(int*)   alloc((size_t)2*N_*4);    // becomes gpix after k_px3
  int2*   cpix2  =(int2*)  alloc((size_t)2*N_*8);
  int*    slot_of=(int*)   alloc((size_t)2*N_*4);
  int*    nbr    =(int*)   alloc((size_t)2*N_*10*4);
  float*  mcomp  =(float*) alloc((size_t)2*N_*4);    // mcomp..splatE contiguous: one memset
  float4* splat4 =(float4*)alloc((size_t)2*N_*16);
  float*  mcompE =(float*) alloc((size_t)2*N_*4);
  float*  splatE =(float*) alloc((size_t)2*N_*16);
  float*  nA     =(float*) alloc((size_t)2*N_*4);
  float*  nB     =(float*) alloc((size_t)2*N_*4);
  float4* meta4  =(float4*)alloc((size_t)2*N_*16);
  float4* x4     =(float4*)alloc((size_t)2*N_*16);
  float4* r4     =(float4*)alloc((size_t)2*N_*16);
  float4* pA4    =(float4*)alloc((size_t)2*N_*16);
  float4* pB4    =(float4*)alloc((size_t)2*N_*16);
  int*    bcnt   =(int*)   alloc((size_t)G2T_*4);
  int*    boff   =(int*)   alloc((size_t)G2T_*4);
  float4* Ap4    = splat4;        // alias: splat4 dead after k_Ar0
  float*  confr  = (float*)pB4;   // alias: pB4 first written in k_Ap it=0, confr dead after px3

  dim3 blk(256);

  // ---- init scalars (scal, count, scalD) ----
  hipMemsetAsync(wsb, 0, 4096 + 12608*8, stream);

  // ---- CNN ----
  k_maxes<<<128,blk,0,stream>>>((const float4*)image,(const float4*)feature,scal);

  k_convT<true,false,false,3,3,4,2,true,384,512,192,256><<<(B_*192*256)/256,blk,0,stream>>>(
      image,pred,w1,b1,x1,gnAcc(0),scal, nullptr,nullptr,nullptr, nullptr,nullptr,nullptr);
  k_convT<false,true,false,16,0,4,2,true,192,256,96,128><<<(B_*96*128)/256,blk,0,stream>>>(
      x1,x1,w2,b2,x2,gnAcc(1),scal, gnAcc(0),g1,be1, nullptr,nullptr,nullptr);
  k_convT<false,true,false,16,0,3,1,false,96,128,96,128><<<(B_*96*128)/256,blk,0,stream>>>(
      x2,x2,wd1,bd1,dx1,gnAcc(2),scal, gnAcc(1),g2,be2, nullptr,nullptr,nullptr);
  k_resizeGN<<<(B_*16*192*256)/256,blk,0,stream>>>(dx1, dx1r, gnAcc(2), gd1, bed1, 96,128, 192,256);
  k_convT<false,false,true,16,16,3,1,false,192,256,192,256><<<(B_*192*256)/256,blk,0,stream>>>(
      dx1r,x1,wd2,bd2,dx2,gnAcc(3),scal, nullptr,nullptr,nullptr, gnAcc(0),g1,be1);
  k_resizeGN<<<(B_*16*N_)/256,blk,0,stream>>>(dx2, dx2r, gnAcc(3), gd2, bed2, 192,256, 384,512);

  k_conv5<<<(B_*(N_/2))/256,blk,0,stream>>>(dx2r, wf, bf, confr, scal);

  // ---- bilateral solver setup ----
  hipMemsetAsync(winner, 0xFF, (size_t)2*T_*4, stream);                      // winner = -1
  hipMemsetAsync(cidx2,  0xFF, (size_t)2*T_*8, stream);                      // .y=-1 = unoccupied
  hipMemsetAsync(mcomp,  0,    (size_t)2*N_*40, stream);                     // mcomp+splat4+mcompE+splatE
  k_px1<<<G2N_,blk,0,stream>>>(feature,scal,hpix,cpix2,winner);
  k_cnt<<<G2T_,blk,0,stream>>>(winner,bcnt);
  k_scan<<<1,blk,0,stream>>>(bcnt,boff,count);
  k_cmp<<<G2T_,blk,0,stream>>>(winner,boff,cidx2,slot_of);
  k_px3<<<G2N_,blk,0,stream>>>(hpix,cidx2,confr,scal,confout,pred,mcomp,splat4,mcompE,splatE);

  // ---- bistochastization: fused extras-merge + nbr-build + it0, then 9 more ----
  k_bisto0<<<G2N_,blk,0,stream>>>(count,slot_of,cpix2,cidx2,nbr,mcomp,mcompE,splat4,(const float4*)splatE,nA);
  for(int it=1; it<10; ++it){
    float* src = (it&1) ? nA : nB;
    float* dst = (it&1) ? nB : nA;
    k_bisto<<<G2N_,blk,0,stream>>>(count,nbr,src,dst,mcomp);
  }
  float* nfin = nB;   // it9 (odd) wrote nB

  k_Ar0<<<G2N_,blk,0,stream>>>(count,nbr,nfin,splat4,meta4,x4,r4,pA4,rzArr(0));

  float4* pbuf[2]={pA4,pB4};
  for(int it=0; it<12; ++it){
    const double* bN = (it==0) ? zeroD : rzArr(it);
    const double* bD = (it==0) ? zeroD : rzArr(it-1);
    int bstr = (it==0) ? 0 : RZB_;
    k_Ap<<<G2N_,blk,0,stream>>>(count,nbr,meta4,r4,pbuf[it&1],pbuf[(it+1)&1],Ap4,bN,bD,bstr,pApArr(it));
    k_upd1<<<G2N_,blk,0,stream>>>(count,x4,r4,pbuf[(it+1)&1],Ap4,rzArr(it),pApArr(it),rzArr(it+1),(it<11)?1:0);
  }
  k_out<<<G2N_,blk,0,stream>>>(x4,hpix,outp);

  (void)in_sizes; (void)n_in; (void)out_size; (void)ws_size;
}